// Round 9
// baseline (36831.311 us; speedup 1.0000x reference)
//
#include <hip/hip_runtime.h>
#include <cstdint>

#define NBLK 256
#define BLOCK 512
#define ROWS 16            // hidden rows per block: 256*16 = 4096
#define HDIM 4096
#define IDIM 64
#define ODIM 16
#define TSTEPS 4096
#define PAD 576            // 18 groups * 32 slots (bank-dealt ELL)
#define GMAX 18
#define LEAK 0.9f
#define SUN 8              // s units per producer (1 per wave: {s0,s1,tag,pad})
#define YUN 8              // y unit stride per producer (units 0-3 data, 4 tag)

typedef float f32x4 __attribute__((ext_vector_type(4)));

// zero the tagged-exchange region every launch (tags use ==, 0/poison never match)
__global__ void init_ws(float* ws) {
    int i = blockIdx.x * blockDim.x + threadIdx.x;
    if (i < 2 * NBLK * (SUN + YUN) * 4) ws[i] = 0.0f;
}

__global__ __launch_bounds__(BLOCK) void esn_kernel(
    const float* __restrict__ X,     // [T][I]
    const float* __restrict__ Win,   // [H][I]
    const float* __restrict__ Wres,  // [H][H]
    const float* __restrict__ bvec,  // [H]
    const float* __restrict__ Wfb,   // [H][O]
    const float* __restrict__ Wout,  // [O][H]
    float* __restrict__ out,         // results [T][O] then outputs [T][H]
    float* __restrict__ sx,          // [2][NBLK][SUN] tagged f32x4 units (s exchange)
    float* __restrict__ yx)          // [2][NBLK][YUN] f32x4 units (y: 4 data + tag)
{
    __shared__ float          ell_val[ROWS][PAD];   // 36864 B
    __shared__ unsigned short ell_idx[ROWS][PAD];   // 18432 B
    __shared__ __align__(16) float s_lds[HDIM];     // 16384 B
    __shared__ float          win_lds[ROWS][IDIM];  //  4096 B
    __shared__ float          wfb_lds[ROWS][ODIM];  //  1024 B
    __shared__ float          wout_lds[ROWS][ODIM]; //  1024 B ([r][o])
    __shared__ float          b_lds[ROWS];
    __shared__ float          x_lds[2][IDIM];       // double-buffered (no B-sync)
    __shared__ __align__(16) float y_lds[ODIM];
    __shared__ float          snew_lds[ROWS];
    __shared__ __align__(16) float ytmp[ODIM];
    __shared__ unsigned       snflag[8];            // per-wave phase-B completion
    __shared__ int            nnz_lds[ROWS];
    __shared__ int            rnds_lds[ROWS];
    __shared__ unsigned short bankCnt[ROWS][32];
    __shared__ unsigned short grpCnt[ROWS][GMAX];

    const int tid   = threadIdx.x;
    const int blk   = blockIdx.x;
    const int rbase = blk * ROWS;

    // ---- pass 0: zero ELL + counters ----
    for (int i = tid; i < ROWS * PAD; i += BLOCK) {
        ell_val[i / PAD][i % PAD] = 0.0f;
        ell_idx[i / PAD][i % PAD] = 0;
    }
    for (int i = tid; i < ROWS * 32; i += BLOCK) bankCnt[i >> 5][i & 31] = 0;
    for (int i = tid; i < ROWS * GMAX; i += BLOCK) grpCnt[i / GMAX][i % GMAX] = 0;

    // ---- pass 1 (parallel): nnz per row ----
    {
        const int wave = tid >> 6, lane = tid & 63;
        for (int rr = wave * 2; rr < wave * 2 + 2; ++rr) {
            const float* wrow = Wres + (size_t)(rbase + rr) * HDIM;
            int cnt = 0;
            for (int c0 = 0; c0 < HDIM; c0 += 64)
                cnt += __popcll(__ballot(wrow[c0 + lane] != 0.0f));
            if (lane == 0) {
                int nz = cnt < PAD ? cnt : PAD;
                nnz_lds[rr] = nz;
                int gu = (nz + 31) >> 5;
                if (gu < 1) gu = 1;
                if (gu > GMAX) gu = GMAX;
                rnds_lds[rr] = (gu + 1) >> 1;
            }
        }
    }
    __syncthreads();

    // ---- pass 2 (serial per row, deterministic): bank-balanced deal ----
    {
        const int wave = tid >> 6, lane = tid & 63;
        if (lane == 0 || lane == 32) {
            const int row = wave * 2 + (lane >> 5);
            const int nz  = nnz_lds[row];
            int gu = (nz + 31) >> 5;
            if (gu < 1) gu = 1;
            if (gu > GMAX) gu = GMAX;
            const float* wrow = Wres + (size_t)(rbase + row) * HDIM;
            int placed = 0;
            for (int c = 0; c < HDIM && placed < nz; ++c) {
                const float w = wrow[c];
                if (w != 0.0f) {
                    const int b = c & 31;
                    const int r = bankCnt[row][b];
                    bankCnt[row][b] = (unsigned short)(r + 1);
                    int g = r % gu;
                    int p = grpCnt[row][g];
                    int guard = 0;
                    while (p >= 32 && guard < GMAX) {
                        g = (g + 1 == gu) ? 0 : g + 1;
                        p = grpCnt[row][g];
                        ++guard;
                    }
                    if (p >= 32) break;
                    grpCnt[row][g] = (unsigned short)(p + 1);
                    const int slot = ((g >> 1) << 6) + 2 * p + (g & 1);
                    ell_val[row][slot] = w;
                    ell_idx[row][slot] = (unsigned short)c;
                    ++placed;
                }
            }
        }
    }

    // ---- small weights into LDS ----
    for (int i = tid; i < ROWS * IDIM; i += BLOCK)
        win_lds[i >> 6][i & 63] = Win[(size_t)(rbase + (i >> 6)) * IDIM + (i & 63)];
    for (int i = tid; i < ROWS * ODIM; i += BLOCK)
        wfb_lds[i >> 4][i & 15] = Wfb[(size_t)(rbase + (i >> 4)) * ODIM + (i & 15)];
    for (int i = tid; i < ROWS * ODIM; i += BLOCK)   // [r][o] = Wout[o][rbase+r]
        wout_lds[i >> 4][i & 15] = Wout[(size_t)(i & 15) * HDIM + rbase + (i >> 4)];
    if (tid < ROWS) b_lds[tid] = bvec[rbase + tid];

    // ---- prologue: s_{-1}=0, y_{-1}=0, x_0, flags ----
    for (int i = tid; i < HDIM; i += BLOCK) s_lds[i] = 0.0f;
    if (tid < ODIM) y_lds[tid] = 0.0f;
    if (tid < IDIM) x_lds[0][tid] = X[tid];
    if (tid < 8) snflag[tid] = 0u;
    __syncthreads();

    float* out_res = out;
    float* out_s   = out + (size_t)TSTEPS * ODIM;

    const int rowB = tid >> 5;        // 0..15
    const int lB   = tid & 31;
    const int wv   = tid >> 6;        // 0..7
    const int ln   = tid & 63;
    const int RB   = rnds_lds[rowB];

    for (int t = 0; t < TSTEPS; ++t) {
        const unsigned tu = (unsigned)(t + 1);
        const float tagf = __uint_as_float(tu);

        // ---- phase B: pre = Wres@s + Win@x + Wfb@y + b ; s_new; INLINE publish ----
        {
            const float* xb = x_lds[t & 1];
            float a0 = 0.0f, a1 = 0.0f;
            for (int k = 0; k < RB; ++k) {
                const int e = (k << 6) + (lB << 1);
                const float2  v  = *(const float2*)&ell_val[rowB][e];
                const ushort2 ix = *(const ushort2*)&ell_idx[rowB][e];
                a0 += v.x * s_lds[ix.x];
                a1 += v.y * s_lds[ix.y];
            }
            float acc = a0 + a1;
            acc += win_lds[rowB][lB] * xb[lB] + win_lds[rowB][lB + 32] * xb[lB + 32];
            if (lB < ODIM) acc += wfb_lds[rowB][lB] * y_lds[lB];
            acc += __shfl_xor(acc, 16, 32);
            acc += __shfl_xor(acc, 8, 32);
            acc += __shfl_xor(acc, 4, 32);
            acc += __shfl_xor(acc, 2, 32);
            acc += __shfl_xor(acc, 1, 32);
            float sn = 0.0f;
            if (lB == 0) {
                const float pre = acc + b_lds[rowB];
                sn = (1.0f - LEAK) * s_lds[rbase + rowB] + LEAK * tanhf(pre);
                snew_lds[rowB] = sn;
            }
            const float sn1 = __shfl(sn, 32);        // lane 0 gets row 2w+1
            if (ln == 0) {
                f32x4 v; v.x = sn; v.y = sn1; v.z = tagf; v.w = 0.0f;
                float* dst = sx + (((size_t)(t & 1) * NBLK + blk) * SUN + wv) * 4;
                asm volatile("global_store_dwordx4 %0, %1, off sc0 sc1"
                             :: "v"(dst), "v"(v) : "memory");
                float2 o2; o2.x = sn; o2.y = sn1;    // out_s (plain cached store)
                *(float2*)(out_s + (size_t)t * HDIM + rbase + 2 * wv) = o2;
                __hip_atomic_store(&snflag[wv], tu, __ATOMIC_RELEASE,
                                   __HIP_MEMORY_SCOPE_WORKGROUP);
            }
        }
        // NO block barrier here: consumers gated by tag dependencies instead.

        if (wv == 0) {
            // ---- y-publisher: wait own block's 8 waves via LDS flags ----
            for (;;) {
                unsigned f = (ln < 8)
                    ? __hip_atomic_load(&snflag[ln], __ATOMIC_ACQUIRE, __HIP_MEMORY_SCOPE_WORKGROUP)
                    : tu;
                if (__all(f >= tu)) break;
            }
            if (ln < ODIM) {
                float yo = 0.0f;
                #pragma unroll
                for (int r = 0; r < ROWS; ++r) yo += wout_lds[r][ln] * snew_lds[r];
                ytmp[ln] = yo;
            }
            asm volatile("s_waitcnt lgkmcnt(0)" ::: "memory");
            __builtin_amdgcn_sched_barrier(0);
            float* ybw = yx + ((size_t)(t & 1) * NBLK + blk) * YUN * 4;
            if (ln < 4) {
                f32x4 dd = *(const f32x4*)&ytmp[ln * 4];
                asm volatile("global_store_dwordx4 %0, %1, off sc0 sc1"
                             :: "v"(ybw + ln * 4), "v"(dd) : "memory");
            }
            asm volatile("s_waitcnt vmcnt(0)" ::: "memory");   // release order: data before tag
            if (ln == 0) {
                f32x4 tgv; tgv.x = tagf; tgv.y = tagf; tgv.z = tagf; tgv.w = tagf;
                asm volatile("global_store_dwordx4 %0, %1, off sc0 sc1"
                             :: "v"(ybw + 16), "v"(tgv) : "memory");
            }
        } else if (wv == 1) {
            // ---- y-reducer: poll 4 tag units/lane, then bulk-load 16 data units ----
            if (t + 1 < TSTEPS) x_lds[(t + 1) & 1][ln] = X[(size_t)(t + 1) * IDIM + ln];
            const float* yb = yx + (size_t)(t & 1) * NBLK * YUN * 4;
            const int p0 = ln, p1 = ln + 64, p2 = ln + 128, p3 = ln + 192;
            f32x4 tg0, tg1, tg2, tg3;
            for (;;) {
                asm volatile("global_load_dwordx4 %0, %1, off sc0 sc1" : "=v"(tg0) : "v"(yb + (p0 * YUN + 4) * 4));
                asm volatile("global_load_dwordx4 %0, %1, off sc0 sc1" : "=v"(tg1) : "v"(yb + (p1 * YUN + 4) * 4));
                asm volatile("global_load_dwordx4 %0, %1, off sc0 sc1" : "=v"(tg2) : "v"(yb + (p2 * YUN + 4) * 4));
                asm volatile("global_load_dwordx4 %0, %1, off sc0 sc1" : "=v"(tg3) : "v"(yb + (p3 * YUN + 4) * 4));
                asm volatile("s_waitcnt vmcnt(0)" ::: "memory");
                __builtin_amdgcn_sched_barrier(0);
                bool ok = __float_as_uint(tg0.x) == tu && __float_as_uint(tg1.x) == tu
                       && __float_as_uint(tg2.x) == tu && __float_as_uint(tg3.x) == tu;
                if (__all(ok)) break;
            }
            f32x4 d00,d01,d02,d03,d10,d11,d12,d13,d20,d21,d22,d23,d30,d31,d32,d33;
            #define LDY(r, p, j) asm volatile("global_load_dwordx4 %0, %1, off sc0 sc1" \
                : "=v"(r) : "v"(yb + ((p) * YUN + (j)) * 4))
            LDY(d00,p0,0); LDY(d01,p0,1); LDY(d02,p0,2); LDY(d03,p0,3);
            LDY(d10,p1,0); LDY(d11,p1,1); LDY(d12,p1,2); LDY(d13,p1,3);
            LDY(d20,p2,0); LDY(d21,p2,1); LDY(d22,p2,2); LDY(d23,p2,3);
            LDY(d30,p3,0); LDY(d31,p3,1); LDY(d32,p3,2); LDY(d33,p3,3);
            #undef LDY
            asm volatile("s_waitcnt vmcnt(0)" ::: "memory");
            __builtin_amdgcn_sched_barrier(0);
            f32x4 a0 = (d00 + d10) + (d20 + d30);
            f32x4 a1 = (d01 + d11) + (d21 + d31);
            f32x4 a2 = (d02 + d12) + (d22 + d32);
            f32x4 a3 = (d03 + d13) + (d23 + d33);
            #pragma unroll
            for (int m = 1; m < 64; m <<= 1) {
                #pragma unroll
                for (int c = 0; c < 4; ++c) {
                    a0[c] += __shfl_xor(a0[c], m);
                    a1[c] += __shfl_xor(a1[c], m);
                    a2[c] += __shfl_xor(a2[c], m);
                    a3[c] += __shfl_xor(a3[c], m);
                }
            }
            if (ln == 0) {
                if (t + 1 < TSTEPS) {
                    *(f32x4*)&y_lds[0]  = a0; *(f32x4*)&y_lds[4]  = a1;
                    *(f32x4*)&y_lds[8]  = a2; *(f32x4*)&y_lds[12] = a3;
                }
                if (blk == 0) {
                    f32x4* orp = (f32x4*)(out_res + (size_t)t * ODIM);
                    orp[0] = a0; orp[1] = a1; orp[2] = a2; orp[3] = a3;
                }
            }
        } else {
            // ---- s-consumers (waves 2..7): poll tagged units, aligned float2 scatter ----
            if (t + 1 < TSTEPS) {
                const float* sb = sx + (size_t)(t & 1) * NBLK * SUN * 4;
                const int cl = (wv - 2) * 64 + ln;            // 0..383 over 2048 units
                const bool h5 = cl < 128;
                f32x4 v0, v1, v2, v3, v4, v5;
                for (;;) {
                    asm volatile("global_load_dwordx4 %0, %1, off sc0 sc1" : "=v"(v0) : "v"(sb + (size_t)cl * 4));
                    asm volatile("global_load_dwordx4 %0, %1, off sc0 sc1" : "=v"(v1) : "v"(sb + (size_t)(cl +  384) * 4));
                    asm volatile("global_load_dwordx4 %0, %1, off sc0 sc1" : "=v"(v2) : "v"(sb + (size_t)(cl +  768) * 4));
                    asm volatile("global_load_dwordx4 %0, %1, off sc0 sc1" : "=v"(v3) : "v"(sb + (size_t)(cl + 1152) * 4));
                    asm volatile("global_load_dwordx4 %0, %1, off sc0 sc1" : "=v"(v4) : "v"(sb + (size_t)(cl + 1536) * 4));
                    if (h5)
                        asm volatile("global_load_dwordx4 %0, %1, off sc0 sc1" : "=v"(v5) : "v"(sb + (size_t)(cl + 1920) * 4));
                    asm volatile("s_waitcnt vmcnt(0)" ::: "memory");
                    __builtin_amdgcn_sched_barrier(0);
                    bool ok = __float_as_uint(v0.z) == tu && __float_as_uint(v1.z) == tu
                           && __float_as_uint(v2.z) == tu && __float_as_uint(v3.z) == tu
                           && __float_as_uint(v4.z) == tu
                           && (!h5 || __float_as_uint(v5.z) == tu);
                    if (__all(ok)) break;
                }
                #define SCAT(v, U) { const int p_ = (U) >> 3, u_ = (U) & 7;          \
                    float2 s2_; s2_.x = (v).x; s2_.y = (v).y;                         \
                    *(float2*)&s_lds[p_ * ROWS + 2 * u_] = s2_; }
                SCAT(v0, cl); SCAT(v1, cl + 384); SCAT(v2, cl + 768);
                SCAT(v3, cl + 1152); SCAT(v4, cl + 1536);
                if (h5) SCAT(v5, cl + 1920);
                #undef SCAT
            }
        }
        __syncthreads();   // A-sync: s/x/y for t+1 ready
    }
}

extern "C" void kernel_launch(void* const* d_in, const int* in_sizes, int n_in,
                              void* d_out, int out_size, void* d_ws, size_t ws_size,
                              hipStream_t stream) {
    (void)in_sizes; (void)n_in; (void)out_size; (void)ws_size;
    const float* X    = (const float*)d_in[0];
    const float* Win  = (const float*)d_in[1];
    const float* Wres = (const float*)d_in[2];
    const float* b    = (const float*)d_in[3];
    const float* Wfb  = (const float*)d_in[4];
    const float* Wout = (const float*)d_in[5];
    float* out = (float*)d_out;
    float* sx  = (float*)d_ws;                          // 2*256*8*16B = 64 KiB
    float* yx  = (float*)d_ws + 2 * NBLK * SUN * 4;     // 2*256*8*16B = 64 KiB

    const int words = 2 * NBLK * (SUN + YUN) * 4;
    init_ws<<<(words + 255) / 256, 256, 0, stream>>>((float*)d_ws);
    esn_kernel<<<NBLK, BLOCK, 0, stream>>>(X, Win, Wres, b, Wfb, Wout, out, sx, yx);
}

// Round 10
// 23704.263 us; speedup vs baseline: 1.5538x; 1.5538x over previous
//
#include <hip/hip_runtime.h>
#include <cstdint>

#define NBLK 128
#define BLOCK 1024
#define ROWS 32            // hidden rows per block: 128*32 = 4096
#define HDIM 4096
#define IDIM 64
#define ODIM 16
#define TSTEPS 4096
#define PAD 576            // 18 groups * 32 slots (bank-dealt ELL)
#define GMAX 18
#define RNDS 9             // fixed-trip: covers gu <= 18; pads gather s_lds[0]*0
#define LEAK 0.9f
#define SU 11              // s units per producer: 3 vals + tag each (unit 10: 2 vals)
#define SUS 12             // s unit stride per producer (pad to 192B)
#define YU 8               // y units per producer: 2 vals + tag + pad

typedef float f32x4 __attribute__((ext_vector_type(4)));

// zero the tagged-exchange region every launch (tags use ==, so 0 never matches)
__global__ void init_ws(float* ws) {
    int i = blockIdx.x * blockDim.x + threadIdx.x;
    if (i < (2 * NBLK * SUS + 2 * NBLK * YU) * 4) ws[i] = 0.0f;
}

__global__ __launch_bounds__(BLOCK) void esn_kernel(
    const float* __restrict__ X,     // [T][I]
    const float* __restrict__ Win,   // [H][I]
    const float* __restrict__ Wres,  // [H][H]
    const float* __restrict__ bvec,  // [H]
    const float* __restrict__ Wfb,   // [H][O]
    const float* __restrict__ Wout,  // [O][H]
    float* __restrict__ out,         // results [T][O] then outputs [T][H]
    float* __restrict__ sx,          // [2][NBLK][SUS] tagged f32x4 units (s exchange)
    float* __restrict__ yx)          // [2][NBLK][YU]  tagged f32x4 units (y partials)
{
    __shared__ float          ell_val[ROWS][PAD];   // 73728 B (build-time only)
    __shared__ unsigned short ell_idx[ROWS][PAD];   // 36864 B (build-time only)
    __shared__ __align__(16) float s_lds[HDIM];     // 16384 B
    __shared__ float          win_lds[ROWS][IDIM];
    __shared__ float          wfb_lds[ROWS][ODIM];
    __shared__ __align__(8)  float wout_lds[ROWS][ODIM]; // [r][o]
    __shared__ float          b_lds[ROWS];
    __shared__ float          x_lds[IDIM];
    __shared__ float          y_lds[ODIM];
    __shared__ __align__(16) float snew_lds[ROWS];
    __shared__ int            nnz_lds[ROWS];
    __shared__ unsigned short bankCnt[ROWS][32];
    __shared__ unsigned short grpCnt[ROWS][GMAX];

    const int tid   = threadIdx.x;
    const int blk   = blockIdx.x;
    const int rbase = blk * ROWS;
    const int rowB  = tid >> 5;        // 0..31
    const int lB    = tid & 31;

    // ---- pass 0: zero ELL + counters ----
    for (int i = tid; i < ROWS * PAD; i += BLOCK) {
        ell_val[i / PAD][i % PAD] = 0.0f;
        ell_idx[i / PAD][i % PAD] = 0;
    }
    for (int i = tid; i < ROWS * 32; i += BLOCK) bankCnt[i >> 5][i & 31] = 0;
    for (int i = tid; i < ROWS * GMAX; i += BLOCK) grpCnt[i / GMAX][i % GMAX] = 0;

    // ---- pass 1 (parallel): nnz per row ----
    {
        const int wave = tid >> 6, lane = tid & 63;
        for (int rr = wave * 2; rr < wave * 2 + 2; ++rr) {
            const float* wrow = Wres + (size_t)(rbase + rr) * HDIM;
            int cnt = 0;
            for (int c0 = 0; c0 < HDIM; c0 += 64)
                cnt += __popcll(__ballot(wrow[c0 + lane] != 0.0f));
            if (lane == 0) nnz_lds[rr] = cnt < PAD ? cnt : PAD;
        }
    }
    __syncthreads();

    // ---- pass 2 (serial per row, deterministic): bank-balanced deal ----
    {
        const int wave = tid >> 6, lane = tid & 63;
        if (lane == 0 || lane == 32) {
            const int row = wave * 2 + (lane >> 5);
            const int nz  = nnz_lds[row];
            int gu = (nz + 31) >> 5;
            if (gu < 1) gu = 1;
            if (gu > GMAX) gu = GMAX;
            const float* wrow = Wres + (size_t)(rbase + row) * HDIM;
            int placed = 0;
            for (int c = 0; c < HDIM && placed < nz; ++c) {
                const float w = wrow[c];
                if (w != 0.0f) {
                    const int b = c & 31;
                    const int r = bankCnt[row][b];
                    bankCnt[row][b] = (unsigned short)(r + 1);
                    int g = r % gu;
                    int p = grpCnt[row][g];
                    int guard = 0;
                    while (p >= 32 && guard < GMAX) {
                        g = (g + 1 == gu) ? 0 : g + 1;
                        p = grpCnt[row][g];
                        ++guard;
                    }
                    if (p >= 32) break;
                    grpCnt[row][g] = (unsigned short)(p + 1);
                    const int slot = ((g >> 1) << 6) + 2 * p + (g & 1);
                    ell_val[row][slot] = w;
                    ell_idx[row][slot] = (unsigned short)c;
                    ++placed;
                }
            }
        }
    }

    // ---- small weights into LDS ----
    for (int i = tid; i < ROWS * IDIM; i += BLOCK)
        win_lds[i >> 6][i & 63] = Win[(size_t)(rbase + (i >> 6)) * IDIM + (i & 63)];
    for (int i = tid; i < ROWS * ODIM; i += BLOCK)
        wfb_lds[i >> 4][i & 15] = Wfb[(size_t)(rbase + (i >> 4)) * ODIM + (i & 15)];
    for (int i = tid; i < ROWS * ODIM; i += BLOCK)   // [r][o] = Wout[o][rbase+r]
        wout_lds[i >> 4][i & 15] = Wout[(size_t)(i & 15) * HDIM + rbase + (i >> 4)];
    if (tid < ROWS) b_lds[tid] = bvec[rbase + tid];

    // ---- prologue: s_{-1}=0, y_{-1}=0, x_0 ----
    for (int i = tid; i < HDIM; i += BLOCK) s_lds[i] = 0.0f;
    if (tid < ODIM) y_lds[tid] = 0.0f;
    if (tid >= 64 && tid < 128) x_lds[tid - 64] = X[tid - 64];
    __syncthreads();

    // ---- preload ELL slots + input weights into REGISTERS (constant over t) ----
    float2   rv[RNDS];
    unsigned ri[RNDS];
    #pragma unroll
    for (int k = 0; k < RNDS; ++k) {
        const int e = (k << 6) + (lB << 1);
        rv[k] = *(const float2*)&ell_val[rowB][e];
        ri[k] = *(const unsigned*)&ell_idx[rowB][e];   // packed ushort2
    }
    const float winA = win_lds[rowB][lB];
    const float winB = win_lds[rowB][lB + 32];
    const float wfbv = (lB < ODIM) ? wfb_lds[rowB][lB] : 0.0f;
    const float bias = b_lds[rowB];

    float* out_res = out;
    float* out_s   = out + (size_t)TSTEPS * ODIM;

    const int wv = tid >> 6;
    const int ln = tid & 63;

    for (int t = 0; t < TSTEPS; ++t) {
        const unsigned tu = (unsigned)(t + 1);
        const float tagf = __uint_as_float(tu);

        // ---- phase B: pre = Wres@s + Win@x + Wfb@y + b ; s_new ----
        {
            float a0 = 0.0f, a1 = 0.0f;
            #pragma unroll
            for (int k = 0; k < RNDS; ++k) {
                a0 += rv[k].x * s_lds[ri[k] & 0xffffu];
                a1 += rv[k].y * s_lds[ri[k] >> 16];
            }
            float acc = a0 + a1;
            acc += winA * x_lds[lB] + winB * x_lds[lB + 32];
            if (lB < ODIM) acc += wfbv * y_lds[lB];
            acc += __shfl_xor(acc, 16, 32);
            acc += __shfl_xor(acc, 8, 32);
            acc += __shfl_xor(acc, 4, 32);
            acc += __shfl_xor(acc, 2, 32);
            acc += __shfl_xor(acc, 1, 32);
            if (lB == 0) {
                const float pre = acc + bias;
                snew_lds[rowB] = (1.0f - LEAK) * s_lds[rbase + rowB] + LEAK * tanhf(pre);
            }
        }
        __syncthreads();   // B-sync: snew_lds ready; s/x/y_lds free

        if (wv == 0) {
            // ---- publish: tagged s units, y units, out_s ----
            if (ln >= 16 && ln < 16 + SU) {            // 11 lanes: s units
                const int j  = ln - 16;
                const int b0 = 3 * j;
                const int b1 = (3 * j + 1 < 32) ? 3 * j + 1 : 31;
                const int b2 = (3 * j + 2 < 32) ? 3 * j + 2 : 31;
                f32x4 v;
                v.x = snew_lds[b0]; v.y = snew_lds[b1]; v.z = snew_lds[b2]; v.w = tagf;
                float* dst = sx + (((size_t)(t & 1) * NBLK + blk) * SUS + j) * 4;
                asm volatile("global_store_dwordx4 %0, %1, off sc0 sc1"
                             :: "v"(dst), "v"(v) : "memory");
            }
            if (ln < YU) {                             // 8 lanes: y partial units
                float a0 = 0.0f, a1 = 0.0f;
                #pragma unroll
                for (int r = 0; r < ROWS; ++r) {
                    const float2 w = *(const float2*)&wout_lds[r][2 * ln];
                    a0 += w.x * snew_lds[r];
                    a1 += w.y * snew_lds[r];
                }
                f32x4 v; v.x = a0; v.y = a1; v.z = tagf; v.w = 0.0f;
                float* dst = yx + (((size_t)(t & 1) * NBLK + blk) * YU + ln) * 4;
                asm volatile("global_store_dwordx4 %0, %1, off sc0 sc1"
                             :: "v"(dst), "v"(v) : "memory");
            }
            if (ln >= 32 && ln < 40) {                 // 8 lanes: out_s (write-only)
                const int j = ln - 32;
                *(f32x4*)(out_s + (size_t)t * HDIM + rbase + j * 4) =
                    *(const f32x4*)&snew_lds[j * 4];
            }
        } else if (wv == 1) {
            // ---- y-reduce: poll all 128 producers' tagged units, butterfly ----
            if (t + 1 < TSTEPS) x_lds[ln] = X[(size_t)(t + 1) * IDIM + ln];
            const int u  = ln & 7;
            const int pg = ln >> 3;                    // 8 producer groups of 16
            const float* yb = yx + (size_t)(t & 1) * NBLK * YU * 4;
            f32x4 w0,w1,w2,w3,w4,w5,w6,w7,w8,w9,w10,w11,w12,w13,w14,w15;
            for (;;) {
                #define YL(i) asm volatile("global_load_dwordx4 %0, %1, off sc0 sc1" \
                    : "=v"(w##i) : "v"(yb + (((pg << 4) + i) * YU + u) * 4));
                YL(0) YL(1) YL(2) YL(3) YL(4) YL(5) YL(6) YL(7)
                YL(8) YL(9) YL(10) YL(11) YL(12) YL(13) YL(14) YL(15)
                #undef YL
                asm volatile("s_waitcnt vmcnt(0)" ::: "memory");
                __builtin_amdgcn_sched_barrier(0);
                bool ok = __float_as_uint(w0.z) == tu  && __float_as_uint(w1.z) == tu
                       && __float_as_uint(w2.z) == tu  && __float_as_uint(w3.z) == tu
                       && __float_as_uint(w4.z) == tu  && __float_as_uint(w5.z) == tu
                       && __float_as_uint(w6.z) == tu  && __float_as_uint(w7.z) == tu
                       && __float_as_uint(w8.z) == tu  && __float_as_uint(w9.z) == tu
                       && __float_as_uint(w10.z) == tu && __float_as_uint(w11.z) == tu
                       && __float_as_uint(w12.z) == tu && __float_as_uint(w13.z) == tu
                       && __float_as_uint(w14.z) == tu && __float_as_uint(w15.z) == tu;
                if (__all(ok)) break;
            }
            float acc0 = ((w0.x + w1.x) + (w2.x + w3.x)) + ((w4.x + w5.x) + (w6.x + w7.x))
                       + ((w8.x + w9.x) + (w10.x + w11.x)) + ((w12.x + w13.x) + (w14.x + w15.x));
            float acc1 = ((w0.y + w1.y) + (w2.y + w3.y)) + ((w4.y + w5.y) + (w6.y + w7.y))
                       + ((w8.y + w9.y) + (w10.y + w11.y)) + ((w12.y + w13.y) + (w14.y + w15.y));
            acc0 += __shfl_xor(acc0, 8);  acc1 += __shfl_xor(acc1, 8);
            acc0 += __shfl_xor(acc0, 16); acc1 += __shfl_xor(acc1, 16);
            acc0 += __shfl_xor(acc0, 32); acc1 += __shfl_xor(acc1, 32);
            if (ln < 8) {
                if (t + 1 < TSTEPS) { y_lds[2 * u] = acc0; y_lds[2 * u + 1] = acc1; }
                if (blk == 0) {
                    out_res[(size_t)t * ODIM + 2 * u]     = acc0;
                    out_res[(size_t)t * ODIM + 2 * u + 1] = acc1;
                }
            }
        } else {
            // ---- s-consumer: poll tagged units of this wave's producer slice ----
            if (t + 1 < TSTEPS) {
                const int wi    = wv - 2;                        // 0..13
                const int start = (wi < 2) ? wi * 10 : 20 + (wi - 2) * 9;
                const int count = (wi < 2) ? 10 : 9;             // 2*10 + 12*9 = 128
                const int U     = count * SU;
                const float* sb = sx + (size_t)(t & 1) * NBLK * SUS * 4;
                const int g0 = ln, g1 = ln + 64;
                const int p0 = g0 / SU, u0 = g0 - p0 * SU;
                const bool h1 = g1 < U;
                const int p1 = g1 / SU, u1 = g1 - p1 * SU;
                const float* a0p = sb + (((start + p0) * SUS) + u0) * 4;
                const float* a1p = sb + (((start + p1) * SUS) + u1) * 4;
                f32x4 v0, v1;
                for (;;) {
                    asm volatile("global_load_dwordx4 %0, %1, off sc0 sc1"
                                 : "=v"(v0) : "v"(a0p));
                    if (h1)
                        asm volatile("global_load_dwordx4 %0, %1, off sc0 sc1"
                                     : "=v"(v1) : "v"(a1p));
                    asm volatile("s_waitcnt vmcnt(0)" ::: "memory");
                    __builtin_amdgcn_sched_barrier(0);
                    bool ok = (__float_as_uint(v0.w) == tu) &&
                              (!h1 || __float_as_uint(v1.w) == tu);
                    if (__all(ok)) break;
                }
                {
                    const int c0 = (start + p0) * 32 + u0 * 3;
                    s_lds[c0] = v0.x; s_lds[c0 + 1] = v0.y;
                    if (u0 != SU - 1) s_lds[c0 + 2] = v0.z;
                }
                if (h1) {
                    const int c1 = (start + p1) * 32 + u1 * 3;
                    s_lds[c1] = v1.x; s_lds[c1 + 1] = v1.y;
                    if (u1 != SU - 1) s_lds[c1 + 2] = v1.z;
                }
            }
        }
        __syncthreads();   // A-sync: s/x/y for t+1 ready
    }
}

extern "C" void kernel_launch(void* const* d_in, const int* in_sizes, int n_in,
                              void* d_out, int out_size, void* d_ws, size_t ws_size,
                              hipStream_t stream) {
    (void)in_sizes; (void)n_in; (void)out_size; (void)ws_size;
    const float* X    = (const float*)d_in[0];
    const float* Win  = (const float*)d_in[1];
    const float* Wres = (const float*)d_in[2];
    const float* b    = (const float*)d_in[3];
    const float* Wfb  = (const float*)d_in[4];
    const float* Wout = (const float*)d_in[5];
    float* out = (float*)d_out;
    float* sx  = (float*)d_ws;                          // 2*128*12*16B = 48 KiB
    float* yx  = (float*)d_ws + 2 * NBLK * SUS * 4;     // 2*128*8*16B  = 32 KiB

    const int words = (2 * NBLK * SUS + 2 * NBLK * YU) * 4;
    init_ws<<<(words + 255) / 256, 256, 0, stream>>>((float*)d_ws);
    esn_kernel<<<NBLK, BLOCK, 0, stream>>>(X, Win, Wres, b, Wfb, Wout, out, sx, yx);
}